// Round 9
// baseline (612.347 us; speedup 1.0000x reference)
//
#include <hip/hip_runtime.h>
#include <hip/hip_bf16.h>

typedef __attribute__((ext_vector_type(8))) __bf16 bf16x8;
typedef __attribute__((ext_vector_type(4))) float floatx4;

#define S_LEN 4096
#define NBH   64
#define BM    256   // q rows per block (8 waves x 32)
#define BN    64    // keys per phase
#define KSTR  72    // padded K row stride (shorts)
#define VSTR  72    // padded V^T row stride (shorts)
#define C_SCALE 0.18033688011112042f  // log2(e) / sqrt(64)
#define RESCALE_THR 8.0f              // defer-max threshold (log2 domain)

__device__ __forceinline__ short f2bf(float x) {
  __hip_bfloat16 h = __float2bfloat16(x);
  return *reinterpret_cast<const short*>(&h);
}

// R8 verified compute pieces (key-permuted in-register P->PV, defer-max,
// deferred l-reduction) re-phased into a CROSS-PHASE SOFTWARE PIPELINE:
//   phase p: stage(buf cur); barrier; prefetch(p+1);
//            QK(p)->sacc            [MFMA burst, matrix pipe]
//            PV(p-1) from buf cur^1 [independent MFMA burst — executes while
//                                    softmax below waits on QK results]
//            softmax(p)->pfrag_prev [VALU, overlaps PV tail; rescale (rare,
//                                    defer-max) lands AFTER PV(p-1): correct
//                                    online-softmax order]
//            barrier; cur^=1
// Tail PV after the loop consumes the last pfrag (its buffer is untouched
// after the final phase). Causal waves retire pfrag at their first inactive
// phase via have_prev. 2 barriers / 64 keys = R5 rate (measured harmless, R7).
__global__ __launch_bounds__(512)
void mea_fwd(const float* __restrict__ qp, const float* __restrict__ kp,
             const float* __restrict__ vp, const int* __restrict__ cm,
             float* __restrict__ op)
{
  __shared__ short kL[2][BN * KSTR];   // K tile  [key][d]    (bf16)
  __shared__ short vT[2][64 * VSTR];   // V^T     [d][pvslot] (bf16, key perm + d-rotation)

  const int t    = threadIdx.x;
  const int w    = t >> 6;
  const int lane = t & 63;
  const int lg   = lane >> 4;
  const int l16  = lane & 15;

  const int bh  = blockIdx.y;
  const int qt  = (int)(gridDim.x - 1) - (int)blockIdx.x;  // big blocks first
  const int q0  = qt * BM;
  const int qw0 = q0 + w * 32;            // this wave's first q row
  const long base = (long)bh * S_LEN * 64;
  const int causal = cm[0];

  // staging: 512 threads x 1 key-row x 8 d-elems
  const int skr = t >> 3;                 // key row (0..63)
  const int sd0 = (t & 7) * 8;            // first d (0,8,...,56)
  // pvslot = bit-permuted key slot: p(s)=32*s4+16*s3+8*s2+4*s5+(s&3)
  const int pcol = ((skr >> 4) & 1) * 32 + ((skr >> 3) & 1) * 16 +
                   ((skr >> 2) & 1) * 8  + ((skr >> 5) & 1) * 4 + (skr & 3);
  const int svcol = (pcol + (sd0 >> 4) * 16) & 63;  // + d-dependent bank rotation

  // Q as B-fragments with softmax scale folded in
  bf16x8 qfrag[2][2];
#pragma unroll
  for (int nt = 0; nt < 2; ++nt)
#pragma unroll
    for (int ks = 0; ks < 2; ++ks) {
      const float* qr = qp + base + (long)(qw0 + nt*16 + l16) * 64 + ks*32 + lg*8;
      float4 a = *(const float4*)(qr);
      float4 b = *(const float4*)(qr + 4);
      union { short s[8]; bf16x8 v; } u;
      u.s[0]=f2bf(a.x*C_SCALE); u.s[1]=f2bf(a.y*C_SCALE);
      u.s[2]=f2bf(a.z*C_SCALE); u.s[3]=f2bf(a.w*C_SCALE);
      u.s[4]=f2bf(b.x*C_SCALE); u.s[5]=f2bf(b.y*C_SCALE);
      u.s[6]=f2bf(b.z*C_SCALE); u.s[7]=f2bf(b.w*C_SCALE);
      qfrag[nt][ks] = u.v;
    }

  floatx4 oacc[2][4];
#pragma unroll
  for (int i = 0; i < 2; ++i)
#pragma unroll
    for (int j = 0; j < 4; ++j)
      oacc[i][j] = (floatx4){0.f, 0.f, 0.f, 0.f};

  float m_run[2] = {-__builtin_inff(), -__builtin_inff()};
  float l_run[2] = {0.f, 0.f};   // per-lane PARTIAL sums (reduced in epilogue)

  const int kmax = causal ? (q0 + BM) : S_LEN;
  const int nph  = kmax / BN;

  // ---- prefetch phase 0 into registers ----
  float4 kpre[2], vpre[2];
  {
    const float* kb = kp + base + (long)skr * 64 + sd0;
    kpre[0] = ((const float4*)kb)[0];  kpre[1] = ((const float4*)kb)[1];
    const float* vb = vp + base + (long)skr * 64 + sd0;
    vpre[0] = ((const float4*)vb)[0];  vpre[1] = ((const float4*)vb)[1];
  }

  bf16x8 pfrag_prev[2][2];
  bool have_prev = false;
  int prevbuf = 0;
  int cur = 0;

  for (int p = 0; p < nph; ++p) {

    // ---- stage prefetched regs -> LDS buf[cur] (cvt f32->bf16) ----
    {
      union { short s[8]; uint4 u; } pk;
      pk.s[0]=f2bf(kpre[0].x); pk.s[1]=f2bf(kpre[0].y);
      pk.s[2]=f2bf(kpre[0].z); pk.s[3]=f2bf(kpre[0].w);
      pk.s[4]=f2bf(kpre[1].x); pk.s[5]=f2bf(kpre[1].y);
      pk.s[6]=f2bf(kpre[1].z); pk.s[7]=f2bf(kpre[1].w);
      *(uint4*)(&kL[cur][skr * KSTR + sd0]) = pk.u;

      short vs[8];
      vs[0]=f2bf(vpre[0].x); vs[1]=f2bf(vpre[0].y);
      vs[2]=f2bf(vpre[0].z); vs[3]=f2bf(vpre[0].w);
      vs[4]=f2bf(vpre[1].x); vs[5]=f2bf(vpre[1].y);
      vs[6]=f2bf(vpre[1].z); vs[7]=f2bf(vpre[1].w);
#pragma unroll
      for (int i = 0; i < 8; ++i)
        vT[cur][(sd0 + i) * VSTR + svcol] = vs[i];
    }
    __syncthreads();   // staging visible; prev-phase reads all complete

    // ---- issue next phase's global loads ----
    if (p + 1 < nph) {
      const int kn = (p + 1) * BN;
      const float* kb = kp + base + (long)(kn + skr) * 64 + sd0;
      kpre[0] = ((const float4*)kb)[0];  kpre[1] = ((const float4*)kb)[1];
      const float* vb = vp + base + (long)(kn + skr) * 64 + sd0;
      vpre[0] = ((const float4*)vb)[0];  vpre[1] = ((const float4*)vb)[1];
    }

    const int  k0  = p * BN;
    const bool act = !(causal && k0 >= qw0 + 32);   // wave-uniform

    // ---- QK(p): S^T = K * Q^T (C[row=key][col=q], log2 domain) ----
    floatx4 sacc[4][2];
    if (act) {
#pragma unroll
      for (int mt = 0; mt < 4; ++mt)
#pragma unroll
        for (int nt = 0; nt < 2; ++nt)
          sacc[mt][nt] = (floatx4){0.f, 0.f, 0.f, 0.f};
#pragma unroll
      for (int ks = 0; ks < 2; ++ks)
#pragma unroll
        for (int mt = 0; mt < 4; ++mt) {
          bf16x8 kfrag = *(const bf16x8*)(&kL[cur][(mt*16 + l16) * KSTR + ks*32 + lg*8]);
#pragma unroll
          for (int nt = 0; nt < 2; ++nt)
            sacc[mt][nt] = __builtin_amdgcn_mfma_f32_16x16x32_bf16(kfrag, qfrag[nt][ks], sacc[mt][nt], 0, 0, 0);
        }
    }

    // ---- PV(p-1): independent MFMA burst, overlaps the sacc wait below ----
    if (have_prev) {
#pragma unroll
      for (int ks = 0; ks < 2; ++ks) {
        bf16x8 vfrag[4];
#pragma unroll
        for (int nd = 0; nd < 4; ++nd) {
          int colr = (ks*32 + lg*8 + nd*16) & 63;   // un-rotate d-dependent rotation
          vfrag[nd] = *(const bf16x8*)(&vT[cur ^ 1][(nd*16 + l16) * VSTR + colr]);
        }
#pragma unroll
        for (int mo = 0; mo < 2; ++mo)
#pragma unroll
          for (int nd = 0; nd < 4; ++nd)
            oacc[mo][nd] = __builtin_amdgcn_mfma_f32_16x16x32_bf16(pfrag_prev[mo][ks], vfrag[nd], oacc[mo][nd], 0, 0, 0);
      }
      have_prev = false;
    }

    // ---- softmax(p) -> pfrag_prev (consumed next phase) ----
    if (act) {
      const bool needmask = causal && (k0 + BN - 1 > qw0);
      float pmax[2] = {-__builtin_inff(), -__builtin_inff()};
#pragma unroll
      for (int mt = 0; mt < 4; ++mt)
#pragma unroll
        for (int nt = 0; nt < 2; ++nt)
#pragma unroll
          for (int r = 0; r < 4; ++r) {
            float v = sacc[mt][nt][r];
            if (needmask) {
              int key = k0  + mt*16 + lg*4 + r;
              int q   = qw0 + nt*16 + l16;
              if (q < key) v = -__builtin_inff();
            }
            sacc[mt][nt][r] = v;
            pmax[nt] = fmaxf(pmax[nt], v);
          }

      // defer-max: rescale only if per-lane max grew past THR
      // (NaN on first tile makes the test false -> rescale path)
      const bool nore = __all(fmaxf(pmax[0] - m_run[0], pmax[1] - m_run[1]) <= RESCALE_THR);
      if (!nore) {
#pragma unroll
        for (int nt = 0; nt < 2; ++nt) {
          pmax[nt] = fmaxf(pmax[nt], __shfl_xor(pmax[nt], 16));
          pmax[nt] = fmaxf(pmax[nt], __shfl_xor(pmax[nt], 32));
        }
        float alpha[2];
#pragma unroll
        for (int nt = 0; nt < 2; ++nt) {
          float mnew = fmaxf(m_run[nt], pmax[nt]);
          alpha[nt]  = __builtin_amdgcn_exp2f(m_run[nt] - mnew);
          m_run[nt]  = mnew;
          l_run[nt] *= alpha[nt];
        }
        // rescale O (after PV(p-1) accumulated — correct online order)
#pragma unroll
        for (int mo = 0; mo < 2; ++mo)
#pragma unroll
          for (int r = 0; r < 4; ++r) {
            float al = __shfl(alpha[mo], lg*4 + r);
#pragma unroll
            for (int nd = 0; nd < 4; ++nd)
              oacc[mo][nd][r] *= al;
          }
      }

      // exp (bounded by 2^THR) + pack P into PV A-fragments (key perm)
      float rsum[2] = {0.f, 0.f};
#pragma unroll
      for (int nt = 0; nt < 2; ++nt)
#pragma unroll
        for (int ks = 0; ks < 2; ++ks) {
          union { short s[8]; bf16x8 v; } pk;
#pragma unroll
          for (int r = 0; r < 4; ++r) {
            float e0 = __builtin_amdgcn_exp2f(sacc[ks][nt][r]     - m_run[nt]);
            float e1 = __builtin_amdgcn_exp2f(sacc[ks + 2][nt][r] - m_run[nt]);
            rsum[nt] += e0 + e1;
            pk.s[r]     = f2bf(e0);
            pk.s[4 + r] = f2bf(e1);
          }
          pfrag_prev[nt][ks] = pk.v;
        }
#pragma unroll
      for (int nt = 0; nt < 2; ++nt)
        l_run[nt] += rsum[nt];   // per-lane partial; reduced in epilogue

      have_prev = true;
      prevbuf   = cur;
    }

    __syncthreads();   // all reads of both buffers done before next writes
    cur ^= 1;
  }

  // ---- tail PV: last pfrag (its buffer untouched after final phase) ----
  if (have_prev) {
#pragma unroll
    for (int ks = 0; ks < 2; ++ks) {
      bf16x8 vfrag[4];
#pragma unroll
      for (int nd = 0; nd < 4; ++nd) {
        int colr = (ks*32 + lg*8 + nd*16) & 63;
        vfrag[nd] = *(const bf16x8*)(&vT[prevbuf][(nd*16 + l16) * VSTR + colr]);
      }
#pragma unroll
      for (int mo = 0; mo < 2; ++mo)
#pragma unroll
        for (int nd = 0; nd < 4; ++nd)
          oacc[mo][nd] = __builtin_amdgcn_mfma_f32_16x16x32_bf16(pfrag_prev[mo][ks], vfrag[nd], oacc[mo][nd], 0, 0, 0);
    }
  }

  // ---- epilogue: reduce partial l across lg copies, then O / l ----
#pragma unroll
  for (int nt = 0; nt < 2; ++nt) {
    l_run[nt] += __shfl_xor(l_run[nt], 16);
    l_run[nt] += __shfl_xor(l_run[nt], 32);
  }
#pragma unroll
  for (int mo = 0; mo < 2; ++mo)
#pragma unroll
    for (int r = 0; r < 4; ++r) {
      float lv  = __shfl(l_run[mo], lg*4 + r);
      float inv = __builtin_amdgcn_rcpf(lv);
      int qrow  = qw0 + mo*16 + lg*4 + r;
#pragma unroll
      for (int nd = 0; nd < 4; ++nd)
        op[base + (long)qrow * 64 + nd*16 + l16] = oacc[mo][nd][r] * inv;
    }
}

extern "C" void kernel_launch(void* const* d_in, const int* in_sizes, int n_in,
                              void* d_out, int out_size, void* d_ws, size_t ws_size,
                              hipStream_t stream) {
  const float* q = (const float*)d_in[0];
  const float* k = (const float*)d_in[1];
  const float* v = (const float*)d_in[2];
  const int*  cm = (const int*)d_in[3];
  float* o = (float*)d_out;
  dim3 grid(S_LEN / BM, NBH);
  mea_fwd<<<grid, dim3(512, 1, 1), 0, stream>>>(q, k, v, cm, o);
}